// Round 1
// baseline (1203.906 us; speedup 1.0000x reference)
//
#include <hip/hip_runtime.h>
#include <stdint.h>

#define TEMP_F 100.0f
#define NEG_F (-1e30f)
#define THRESH2_F 10000.0f

// Pack (float value, index) into u64 so that u64-max == (max value, min index on tie).
// Float mapped to order-preserving uint; index stored as ~idx so larger packed = smaller idx.
__device__ __forceinline__ unsigned long long packvi(float v, int idx) {
    unsigned u = __float_as_uint(v);
    u = (u & 0x80000000u) ? ~u : (u | 0x80000000u);
    return (((unsigned long long)u) << 32) | (unsigned long long)(0xFFFFFFFFu - (unsigned)idx);
}
__device__ __forceinline__ unsigned long long u64max(unsigned long long a, unsigned long long b) {
    return a > b ? a : b;
}

// ---------------- init: zero accumulators, seed colPacked with (NEG,0), compute T21 ----------------
__global__ void init_kernel(const float* __restrict__ Tiv,
                            unsigned long long* __restrict__ colPacked,
                            float* __restrict__ acc, float* __restrict__ T21,
                            int B, int N) {
    int idx = blockIdx.x * 256 + threadIdx.x;
    if (idx < B * N) colPacked[idx] = packvi(NEG_F, 0);
    if (idx < B * 3) acc[idx] = 0.0f;
    if (idx < B) {
        // T21 = se3_inv(T_tgt) @ T_src  (rows 0..2, all 4 cols; T_src bottom row is arbitrary!)
        const float* Ts = Tiv + (size_t)(2 * idx) * 16;
        const float* Tt = Tiv + (size_t)(2 * idx + 1) * 16;
        float* T = T21 + idx * 12;
        for (int i = 0; i < 3; i++) {
            // M[i][k] = R[k][i] for k<3 ; M[i][3] = -sum_k R[k][i]*t[k]
            float mi3 = -(Tt[0 * 4 + i] * Tt[0 * 4 + 3] +
                          Tt[1 * 4 + i] * Tt[1 * 4 + 3] +
                          Tt[2 * 4 + i] * Tt[2 * 4 + 3]);
            for (int j = 0; j < 4; j++) {
                T[i * 4 + j] = Tt[0 * 4 + i] * Ts[0 * 4 + j] +
                               Tt[1 * 4 + i] * Ts[1 * 4 + j] +
                               Tt[2 * 4 + i] * Ts[2 * 4 + j] +
                               mi3 * Ts[3 * 4 + j];
            }
        }
    }
}

// ---------------- row pass: online masked softmax fused with soft@tgt.T, plus row argmax ----------------
__global__ __launch_bounds__(256) void rows_kernel(const float* __restrict__ wv,
                                                   const float* __restrict__ tgt,
                                                   const int* __restrict__ pm,
                                                   float* __restrict__ points2,
                                                   unsigned* __restrict__ ind2to1,
                                                   int N) {
    const int b = blockIdx.y;
    const int i = blockIdx.x;
    const float* row = wv + ((size_t)b * N + i) * N;
    const float* t0 = tgt + (size_t)b * 3 * N;
    const float* t1 = t0 + N;
    const float* t2 = t1 + N;
    const int* m2 = pm + (size_t)(2 * b + 1) * N;

    float m = -INFINITY, s = 0.f, p0 = 0.f, p1 = 0.f, p2 = 0.f;
    unsigned long long best = 0ull;

    for (int j = threadIdx.x; j < N; j += 256) {
        float v = m2[j] ? row[j] : NEG_F;
        best = u64max(best, packvi(v, j));
        float x = TEMP_F * v;
        if (x > m) {
            float sc = __expf(m - x);   // exp(-inf)=0 on first iter: s stays 0
            s *= sc; p0 *= sc; p1 *= sc; p2 *= sc;
            m = x;
        }
        float wgt = __expf(x - m);
        s += wgt;
        p0 += wgt * t0[j];
        p1 += wgt * t1[j];
        p2 += wgt * t2[j];
    }

    __shared__ float sm[256], ss[256], sp0[256], sp1[256], sp2[256];
    __shared__ unsigned long long sb[256];
    const int t = threadIdx.x;
    sm[t] = m; ss[t] = s; sp0[t] = p0; sp1[t] = p1; sp2[t] = p2; sb[t] = best;
    __syncthreads();
    for (int off = 128; off > 0; off >>= 1) {
        if (t < off) {
            float ma = sm[t], mb = sm[t + off];
            float mm = fmaxf(ma, mb);
            float sa = __expf(ma - mm), sc = __expf(mb - mm);
            ss[t]  = ss[t]  * sa + ss[t + off]  * sc;
            sp0[t] = sp0[t] * sa + sp0[t + off] * sc;
            sp1[t] = sp1[t] * sa + sp1[t + off] * sc;
            sp2[t] = sp2[t] * sa + sp2[t + off] * sc;
            sm[t] = mm;
            sb[t] = u64max(sb[t], sb[t + off]);
        }
        __syncthreads();
    }
    if (t == 0) {
        float inv = 1.0f / ss[0];
        size_t o = ((size_t)b * N + i) * 3;
        points2[o + 0] = sp0[0] * inv;
        points2[o + 1] = sp1[0] * inv;
        points2[o + 2] = sp2[0] * inv;
        ind2to1[(size_t)b * N + i] = 0xFFFFFFFFu - (unsigned)(sb[0] & 0xFFFFFFFFull);
    }
}

// ---------------- column pass: masked argmax over rows per column ----------------
// 256 threads = 4 row-offsets x 64 columns; rows with m1==0 skipped (wave-uniform -> no load).
__global__ __launch_bounds__(256) void cols_kernel(const float* __restrict__ wv,
                                                   const int* __restrict__ pm,
                                                   unsigned long long* __restrict__ colPacked,
                                                   int N, int rowsPerSplit) {
    const int b = blockIdx.z;
    const int col = blockIdx.x * 64 + (threadIdx.x & 63);
    const int ro = threadIdx.x >> 6;
    const int* m1 = pm + (size_t)(2 * b) * N;
    const float* base = wv + (size_t)b * N * N;

    unsigned long long best = 0ull;
    int r0 = blockIdx.y * rowsPerSplit;
    int r1 = r0 + rowsPerSplit;
    if (r1 > N) r1 = N;
    if (col < N) {
        for (int i = r0 + ro; i < r1; i += 4) {
            if (m1[i]) {   // wave-uniform: all 64 lanes share i
                float v = base[(size_t)i * N + col];
                best = u64max(best, packvi(v, i));
            }
        }
    }
    __shared__ unsigned long long sb[256];
    sb[threadIdx.x] = best;
    __syncthreads();
    if (ro == 0 && col < N) {
        unsigned long long x = u64max(u64max(sb[threadIdx.x], sb[threadIdx.x + 64]),
                                      u64max(sb[threadIdx.x + 128], sb[threadIdx.x + 192]));
        if (x) atomicMax(&colPacked[(size_t)b * N + col], x);
    }
}

// ---------------- epilogue: mahalanobis + inlier mask + per-pair partial sums ----------------
__global__ __launch_bounds__(256) void loss_kernel(const float* __restrict__ src,
                                                   const float* __restrict__ wts,
                                                   const int* __restrict__ pm,
                                                   const float* __restrict__ points2,
                                                   const unsigned* __restrict__ ind2to1,
                                                   const unsigned long long* __restrict__ colPacked,
                                                   const float* __restrict__ T21,
                                                   float* __restrict__ acc, int N) {
    const int b = blockIdx.y;
    const int i = blockIdx.x * 256 + threadIdx.x;
    float lm = 0.f, ld = 0.f, lc = 0.f;
    if (i < N) {
        const int* m1 = pm + (size_t)(2 * b) * N;
        bool msk = (m1[i] != 0);
        unsigned j = ind2to1[(size_t)b * N + i];
        unsigned i2 = 0xFFFFFFFFu - (unsigned)(colPacked[(size_t)b * N + j] & 0xFFFFFFFFull);
        bool consist = (i2 == (unsigned)i);
        const float* T = T21 + b * 12;
        const float* s0 = src + (size_t)b * 3 * N;
        float x = s0[i], y = s0[N + i], z = s0[2 * (size_t)N + i];
        size_t o = ((size_t)b * N + i) * 3;
        float e0 = T[0] * x + T[1] * y + T[2]  * z + T[3]  - points2[o + 0];
        float e1 = T[4] * x + T[5] * y + T[6]  * z + T[7]  - points2[o + 1];
        float e2 = T[8] * x + T[9] * y + T[10] * z + T[11] - points2[o + 2];
        const float* w = wts + (size_t)b * 6 * N;
        float a  = w[i];
        float bb = w[N + i];
        float c  = w[2 * (size_t)N + i];
        float d0 = w[3 * (size_t)N + i];
        float d1 = w[4 * (size_t)N + i];
        float d2 = w[5 * (size_t)N + i];
        // u = L^T e with L = [[1,0,0],[a,1,0],[bb,c,1]]
        float u0 = e0 + a * e1 + bb * e2;
        float u1 = e1 + c * e2;
        float u2 = e2;
        float mah = expf(d0) * u0 * u0 + expf(d1) * u1 * u1 + expf(d2) * u2 * u2;
        if (msk && consist && (mah < THRESH2_F)) {
            lm = mah; ld = d0 + d1 + d2; lc = 1.0f;
        }
    }
    __shared__ float r0[256], r1[256], r2[256];
    const int t = threadIdx.x;
    r0[t] = lm; r1[t] = ld; r2[t] = lc;
    __syncthreads();
    for (int off = 128; off > 0; off >>= 1) {
        if (t < off) { r0[t] += r0[t + off]; r1[t] += r1[t + off]; r2[t] += r2[t + off]; }
        __syncthreads();
    }
    if (t == 0) {
        atomicAdd(&acc[b * 3 + 0], r0[0]);
        atomicAdd(&acc[b * 3 + 1], r1[0]);
        atomicAdd(&acc[b * 3 + 2], r2[0]);
    }
}

__global__ void finish_kernel(const float* __restrict__ acc, float* __restrict__ out, int B) {
    if (threadIdx.x == 0 && blockIdx.x == 0) {
        float total = 0.f;
        for (int b = 0; b < B; b++) {
            float cnt = fmaxf(acc[b * 3 + 2], 1.0f);
            total += (acc[b * 3 + 0] - acc[b * 3 + 1]) / cnt;
        }
        out[0] = total;
    }
}

extern "C" void kernel_launch(void* const* d_in, const int* in_sizes, int n_in,
                              void* d_out, int out_size, void* d_ws, size_t ws_size,
                              hipStream_t stream) {
    const float* src = (const float*)d_in[0];   // (B,3,N)
    const float* tgt = (const float*)d_in[1];   // (B,3,N)
    const float* wts = (const float*)d_in[2];   // (B,6,N)
    const float* wv  = (const float*)d_in[3];   // (B,N,N)
    const float* Tiv = (const float*)d_in[4];   // (2B,4,4)
    const int*   pm  = (const int*)d_in[5];     // (2B,N)
    float* out = (float*)d_out;

    long long s0 = in_sizes[0], s3 = in_sizes[3];
    int N = (int)(3LL * s3 / s0);               // s3 = B*N*N, s0 = 3*B*N
    int B = (int)(s0 / (3LL * (long long)N));

    // workspace layout (u64 first for alignment)
    char* w = (char*)d_ws;
    unsigned long long* colPacked = (unsigned long long*)w; w += sizeof(unsigned long long) * (size_t)B * N;
    float* points2 = (float*)w;  w += sizeof(float) * (size_t)B * N * 3;
    unsigned* ind2to1 = (unsigned*)w; w += sizeof(unsigned) * (size_t)B * N;
    float* T21 = (float*)w; w += sizeof(float) * (size_t)B * 12;
    float* acc = (float*)w; w += sizeof(float) * (size_t)B * 3;

    int initBlocks = (B * N + 255) / 256;
    init_kernel<<<initBlocks, 256, 0, stream>>>(Tiv, colPacked, acc, T21, B, N);

    dim3 gRows(N, B);
    rows_kernel<<<gRows, 256, 0, stream>>>(wv, tgt, pm, points2, ind2to1, N);

    int colTiles = (N + 63) / 64;
    int rowsPerSplit = (N + 7) / 8;
    dim3 gCols(colTiles, 8, B);
    cols_kernel<<<gCols, 256, 0, stream>>>(wv, pm, colPacked, N, rowsPerSplit);

    dim3 gLoss((N + 255) / 256, B);
    loss_kernel<<<gLoss, 256, 0, stream>>>(src, wts, pm, points2, ind2to1, colPacked, T21, acc, N);

    finish_kernel<<<1, 64, 0, stream>>>(acc, out, B);
}

// Round 2
// 795.515 us; speedup vs baseline: 1.5134x; 1.5134x over previous
//
#include <hip/hip_runtime.h>
#include <stdint.h>

#define TEMP_F 100.0f
#define NEG_F (-1e30f)
#define THRESH2_F 10000.0f

typedef unsigned long long ull;

// Pack (float value, index) into u64 so that u64-max == (max value, min index on tie).
__device__ __forceinline__ ull packvi(float v, int idx) {
    unsigned u = __float_as_uint(v);
    u = (u & 0x80000000u) ? ~u : (u | 0x80000000u);
    return (((ull)u) << 32) | (ull)(0xFFFFFFFFu - (unsigned)idx);
}
__device__ __forceinline__ float unpackv(ull p) {
    unsigned u = (unsigned)(p >> 32);
    u = (u & 0x80000000u) ? (u & 0x7FFFFFFFu) : ~u;
    return __uint_as_float(u);
}
__device__ __forceinline__ ull u64max(ull a, ull b) { return a > b ? a : b; }

// ---------------- init: zero accumulators, seed colPacked, compute T21, zero validCnt ----------------
__global__ void init_kernel(const float* __restrict__ Tiv,
                            ull* __restrict__ colPacked,
                            float* __restrict__ acc, float* __restrict__ T21,
                            int* __restrict__ validCnt,
                            int B, int N) {
    int idx = blockIdx.x * 256 + threadIdx.x;
    if (idx < B * N) colPacked[idx] = packvi(NEG_F, 0);
    if (idx < B * 3) acc[idx] = 0.0f;
    if (idx < B) validCnt[idx] = 0;
    if (idx < B) {
        // T21 = se3_inv(T_tgt) @ T_src  (rows 0..2; T_src bottom row is arbitrary data!)
        const float* Ts = Tiv + (size_t)(2 * idx) * 16;
        const float* Tt = Tiv + (size_t)(2 * idx + 1) * 16;
        float* T = T21 + idx * 12;
        for (int i = 0; i < 3; i++) {
            float mi3 = -(Tt[0 * 4 + i] * Tt[0 * 4 + 3] +
                          Tt[1 * 4 + i] * Tt[1 * 4 + 3] +
                          Tt[2 * 4 + i] * Tt[2 * 4 + 3]);
            for (int j = 0; j < 4; j++) {
                T[i * 4 + j] = Tt[0 * 4 + i] * Ts[0 * 4 + j] +
                               Tt[1 * 4 + i] * Ts[1 * 4 + j] +
                               Tt[2 * 4 + i] * Ts[2 * 4 + j] +
                               mi3 * Ts[3 * 4 + j];
            }
        }
    }
}

// ---------------- compact: list of rows with m1[i]!=0 (order irrelevant: max is commutative) --------
__global__ void compact_kernel(const int* __restrict__ pm,
                               int* __restrict__ validRows, int* __restrict__ validCnt,
                               int N) {
    int b = blockIdx.y;
    int i = blockIdx.x * 256 + threadIdx.x;
    if (i < N && pm[(size_t)(2 * b) * N + i]) {
        int pos = atomicAdd(&validCnt[b], 1);
        validRows[(size_t)b * N + pos] = i;
    }
}

// ---------------- row pass: two-phase (max first, then exp+weighted sum), LDS-staged row -----------
__global__ __launch_bounds__(256) void rows_kernel(const float* __restrict__ wv,
                                                   const float* __restrict__ tgt,
                                                   const int* __restrict__ pm,
                                                   float* __restrict__ points2,
                                                   unsigned* __restrict__ ind2to1,
                                                   int N) {
    const int b = blockIdx.y;
    const int i = blockIdx.x;
    const float* row = wv + ((size_t)b * N + i) * N;
    const float* t0 = tgt + (size_t)b * 3 * N;
    const float* t1 = t0 + N;
    const float* t2 = t1 + N;
    const int* m2 = pm + (size_t)(2 * b + 1) * N;
    const int t = threadIdx.x;
    const int N4 = N >> 2;

    __shared__ float xv[5760];           // x = TEMP * masked v
    __shared__ ull sb[256];

    // ---- phase 1: masked load (vectorized), stage x to LDS, track packed max/argmax ----
    float4* xv4 = (float4*)xv;
    ull best = 0ull;
    for (int j4 = t; j4 < N4; j4 += 256) {
        float4 r = ((const float4*)row)[j4];
        int4 mk = ((const int4*)m2)[j4];
        int j = j4 << 2;
        float v0 = mk.x ? r.x : NEG_F;
        float v1 = mk.y ? r.y : NEG_F;
        float v2 = mk.z ? r.z : NEG_F;
        float v3 = mk.w ? r.w : NEG_F;
        best = u64max(best, u64max(u64max(packvi(v0, j), packvi(v1, j + 1)),
                                   u64max(packvi(v2, j + 2), packvi(v3, j + 3))));
        float4 xs;
        xs.x = TEMP_F * v0; xs.y = TEMP_F * v1; xs.z = TEMP_F * v2; xs.w = TEMP_F * v3;
        xv4[j4] = xs;
    }
    sb[t] = best;
    __syncthreads();
    for (int off = 128; off > 0; off >>= 1) {
        if (t < off) sb[t] = u64max(sb[t], sb[t + off]);
        __syncthreads();
    }
    const ull bfin = sb[0];
    const float M = TEMP_F * unpackv(bfin);   // same product as stored x at the argmax
    __syncthreads();

    // ---- phase 2: exp(x - M), weighted accumulation with vectorized tgt loads ----
    float s = 0.f, p0 = 0.f, p1 = 0.f, p2 = 0.f;
    for (int j4 = t; j4 < N4; j4 += 256) {
        float4 xs = xv4[j4];
        float w0 = __expf(xs.x - M);
        float w1 = __expf(xs.y - M);
        float w2 = __expf(xs.z - M);
        float w3 = __expf(xs.w - M);
        float4 a = ((const float4*)t0)[j4];
        float4 c = ((const float4*)t1)[j4];
        float4 d = ((const float4*)t2)[j4];
        s += (w0 + w1) + (w2 + w3);
        p0 += (w0 * a.x + w1 * a.y) + (w2 * a.z + w3 * a.w);
        p1 += (w0 * c.x + w1 * c.y) + (w2 * c.z + w3 * c.w);
        p2 += (w0 * d.x + w1 * d.y) + (w2 * d.z + w3 * d.w);
    }
    __syncthreads();                      // xv reads done; reuse as reduction scratch
    float* rs = xv;
    rs[t] = s; rs[256 + t] = p0; rs[512 + t] = p1; rs[768 + t] = p2;
    __syncthreads();
    for (int off = 128; off > 0; off >>= 1) {
        if (t < off) {
            rs[t] += rs[t + off];
            rs[256 + t] += rs[256 + t + off];
            rs[512 + t] += rs[512 + t + off];
            rs[768 + t] += rs[768 + t + off];
        }
        __syncthreads();
    }
    if (t == 0) {
        float inv = 1.0f / rs[0];
        size_t o = ((size_t)b * N + i) * 3;
        points2[o + 0] = rs[256] * inv;
        points2[o + 1] = rs[512] * inv;
        points2[o + 2] = rs[768] * inv;
        ind2to1[(size_t)b * N + i] = 0xFFFFFFFFu - (unsigned)(bfin & 0xFFFFFFFFull);
    }
}

// ---------------- column pass: compacted rows, unguarded 8-wide unroll (8 loads in flight) ---------
__global__ __launch_bounds__(256) void cols_kernel(const float* __restrict__ wv,
                                                   const int* __restrict__ validRows,
                                                   const int* __restrict__ validCnt,
                                                   ull* __restrict__ colPacked,
                                                   int N, int S) {
    const int b = blockIdx.z;
    const int col = blockIdx.x * 256 + threadIdx.x;
    if (col >= N) return;
    const int cnt = validCnt[b];
    const int per = (cnt + S - 1) / S;
    int k0 = blockIdx.y * per;
    int k1 = k0 + per; if (k1 > cnt) k1 = cnt;
    const int* vr = validRows + (size_t)b * N;
    const float* base = wv + (size_t)b * N * N + col;

    ull best = 0ull;
    int k = k0;
    for (; k + 8 <= k1; k += 8) {
        int i0 = vr[k + 0], i1 = vr[k + 1], i2 = vr[k + 2], i3 = vr[k + 3];
        int i4 = vr[k + 4], i5 = vr[k + 5], i6 = vr[k + 6], i7 = vr[k + 7];
        float v0 = base[(size_t)i0 * N];
        float v1 = base[(size_t)i1 * N];
        float v2 = base[(size_t)i2 * N];
        float v3 = base[(size_t)i3 * N];
        float v4 = base[(size_t)i4 * N];
        float v5 = base[(size_t)i5 * N];
        float v6 = base[(size_t)i6 * N];
        float v7 = base[(size_t)i7 * N];
        ull b0 = u64max(packvi(v0, i0), packvi(v1, i1));
        ull b1 = u64max(packvi(v2, i2), packvi(v3, i3));
        ull b2 = u64max(packvi(v4, i4), packvi(v5, i5));
        ull b3 = u64max(packvi(v6, i6), packvi(v7, i7));
        best = u64max(best, u64max(u64max(b0, b1), u64max(b2, b3)));
    }
    for (; k < k1; k++) {
        int i0 = vr[k];
        best = u64max(best, packvi(base[(size_t)i0 * N], i0));
    }
    if (best) atomicMax(&colPacked[(size_t)b * N + col], best);
}

// ---------------- epilogue: mahalanobis + inlier mask + per-pair partial sums ----------------
__global__ __launch_bounds__(256) void loss_kernel(const float* __restrict__ src,
                                                   const float* __restrict__ wts,
                                                   const int* __restrict__ pm,
                                                   const float* __restrict__ points2,
                                                   const unsigned* __restrict__ ind2to1,
                                                   const ull* __restrict__ colPacked,
                                                   const float* __restrict__ T21,
                                                   float* __restrict__ acc, int N) {
    const int b = blockIdx.y;
    const int i = blockIdx.x * 256 + threadIdx.x;
    float lm = 0.f, ld = 0.f, lc = 0.f;
    if (i < N) {
        const int* m1 = pm + (size_t)(2 * b) * N;
        bool msk = (m1[i] != 0);
        unsigned j = ind2to1[(size_t)b * N + i];
        unsigned i2 = 0xFFFFFFFFu - (unsigned)(colPacked[(size_t)b * N + j] & 0xFFFFFFFFull);
        bool consist = (i2 == (unsigned)i);
        const float* T = T21 + b * 12;
        const float* s0 = src + (size_t)b * 3 * N;
        float x = s0[i], y = s0[N + i], z = s0[2 * (size_t)N + i];
        size_t o = ((size_t)b * N + i) * 3;
        float e0 = T[0] * x + T[1] * y + T[2]  * z + T[3]  - points2[o + 0];
        float e1 = T[4] * x + T[5] * y + T[6]  * z + T[7]  - points2[o + 1];
        float e2 = T[8] * x + T[9] * y + T[10] * z + T[11] - points2[o + 2];
        const float* w = wts + (size_t)b * 6 * N;
        float a  = w[i];
        float bb = w[N + i];
        float c  = w[2 * (size_t)N + i];
        float d0 = w[3 * (size_t)N + i];
        float d1 = w[4 * (size_t)N + i];
        float d2 = w[5 * (size_t)N + i];
        float u0 = e0 + a * e1 + bb * e2;
        float u1 = e1 + c * e2;
        float u2 = e2;
        float mah = expf(d0) * u0 * u0 + expf(d1) * u1 * u1 + expf(d2) * u2 * u2;
        if (msk && consist && (mah < THRESH2_F)) {
            lm = mah; ld = d0 + d1 + d2; lc = 1.0f;
        }
    }
    __shared__ float r0[256], r1[256], r2[256];
    const int t = threadIdx.x;
    r0[t] = lm; r1[t] = ld; r2[t] = lc;
    __syncthreads();
    for (int off = 128; off > 0; off >>= 1) {
        if (t < off) { r0[t] += r0[t + off]; r1[t] += r1[t + off]; r2[t] += r2[t + off]; }
        __syncthreads();
    }
    if (t == 0) {
        atomicAdd(&acc[b * 3 + 0], r0[0]);
        atomicAdd(&acc[b * 3 + 1], r1[0]);
        atomicAdd(&acc[b * 3 + 2], r2[0]);
    }
}

__global__ void finish_kernel(const float* __restrict__ acc, float* __restrict__ out, int B) {
    if (threadIdx.x == 0 && blockIdx.x == 0) {
        float total = 0.f;
        for (int b = 0; b < B; b++) {
            float cnt = fmaxf(acc[b * 3 + 2], 1.0f);
            total += (acc[b * 3 + 0] - acc[b * 3 + 1]) / cnt;
        }
        out[0] = total;
    }
}

extern "C" void kernel_launch(void* const* d_in, const int* in_sizes, int n_in,
                              void* d_out, int out_size, void* d_ws, size_t ws_size,
                              hipStream_t stream) {
    const float* src = (const float*)d_in[0];   // (B,3,N)
    const float* tgt = (const float*)d_in[1];   // (B,3,N)
    const float* wts = (const float*)d_in[2];   // (B,6,N)
    const float* wv  = (const float*)d_in[3];   // (B,N,N)
    const float* Tiv = (const float*)d_in[4];   // (2B,4,4)
    const int*   pm  = (const int*)d_in[5];     // (2B,N)
    float* out = (float*)d_out;

    long long s0 = in_sizes[0], s3 = in_sizes[3];
    int N = (int)(3LL * s3 / s0);
    int B = (int)(s0 / (3LL * (long long)N));

    // workspace layout (u64 first for alignment)
    char* w = (char*)d_ws;
    ull* colPacked = (ull*)w;        w += sizeof(ull) * (size_t)B * N;
    float* points2 = (float*)w;      w += sizeof(float) * (size_t)B * N * 3;
    unsigned* ind2to1 = (unsigned*)w; w += sizeof(unsigned) * (size_t)B * N;
    int* validRows = (int*)w;        w += sizeof(int) * (size_t)B * N;
    int* validCnt = (int*)w;         w += sizeof(int) * (size_t)B;
    float* T21 = (float*)w;          w += sizeof(float) * (size_t)B * 12;
    float* acc = (float*)w;          w += sizeof(float) * (size_t)B * 3;

    int nb = (N + 255) / 256;
    init_kernel<<<(B * N + 255) / 256, 256, 0, stream>>>(Tiv, colPacked, acc, T21, validCnt, B, N);
    compact_kernel<<<dim3(nb, B), 256, 0, stream>>>(pm, validRows, validCnt, N);

    dim3 gRows(N, B);
    rows_kernel<<<gRows, 256, 0, stream>>>(wv, tgt, pm, points2, ind2to1, N);

    const int S = 8;  // row splits per column tile
    dim3 gCols(nb, S, B);
    cols_kernel<<<gCols, 256, 0, stream>>>(wv, validRows, validCnt, colPacked, N, S);

    dim3 gLoss(nb, B);
    loss_kernel<<<gLoss, 256, 0, stream>>>(src, wts, pm, points2, ind2to1, colPacked, T21, acc, N);

    finish_kernel<<<1, 64, 0, stream>>>(acc, out, B);
}

// Round 3
// 710.849 us; speedup vs baseline: 1.6936x; 1.1191x over previous
//
#include <hip/hip_runtime.h>
#include <stdint.h>

#define TEMP_F 100.0f
#define NEG_F (-1e30f)
#define XNEG_F (-1e32f)          // TEMP * NEG, exact fp32 product
#define THRESH2_F 10000.0f

typedef unsigned long long ull;

// Pack (float value, index) into u64 so that u64-max == (max value, min index on tie).
__device__ __forceinline__ ull packvi(float v, int idx) {
    unsigned u = __float_as_uint(v);
    u = (u & 0x80000000u) ? ~u : (u | 0x80000000u);
    return (((ull)u) << 32) | (ull)(0xFFFFFFFFu - (unsigned)idx);
}
__device__ __forceinline__ ull u64max(ull a, ull b) { return a > b ? a : b; }

// ---------------- init: seed colPacked, zero acc/validCnt, compute T21 ----------------
__global__ void init_kernel(const float* __restrict__ Tiv,
                            ull* __restrict__ colPacked,
                            float* __restrict__ acc, float* __restrict__ T21,
                            int* __restrict__ validCnt,
                            int B, int N) {
    int idx = blockIdx.x * 256 + threadIdx.x;
    if (idx < B * N) colPacked[idx] = packvi(NEG_F, 0);
    if (idx < B * 3) acc[idx] = 0.0f;
    if (idx < B) validCnt[idx] = 0;
    if (idx < B) {
        // T21 = se3_inv(T_tgt) @ T_src (rows 0..2; T_src bottom row is arbitrary data!)
        const float* Ts = Tiv + (size_t)(2 * idx) * 16;
        const float* Tt = Tiv + (size_t)(2 * idx + 1) * 16;
        float* T = T21 + idx * 12;
        for (int i = 0; i < 3; i++) {
            float mi3 = -(Tt[0 * 4 + i] * Tt[0 * 4 + 3] +
                          Tt[1 * 4 + i] * Tt[1 * 4 + 3] +
                          Tt[2 * 4 + i] * Tt[2 * 4 + 3]);
            for (int j = 0; j < 4; j++) {
                T[i * 4 + j] = Tt[0 * 4 + i] * Ts[0 * 4 + j] +
                               Tt[1 * 4 + i] * Ts[1 * 4 + j] +
                               Tt[2 * 4 + i] * Ts[2 * 4 + j] +
                               mi3 * Ts[3 * 4 + j];
            }
        }
    }
}

// ---------------- compact: rows with m1[i]!=0 (order irrelevant; every use is commutative) ---------
__global__ void compact_kernel(const int* __restrict__ pm,
                               int* __restrict__ validRows, int* __restrict__ validCnt,
                               int N) {
    int b = blockIdx.y;
    int i = blockIdx.x * 256 + threadIdx.x;
    if (i < N && pm[(size_t)(2 * b) * N + i]) {
        int pos = atomicAdd(&validCnt[b], 1);
        validRows[(size_t)b * N + pos] = i;
    }
}

// ---------------- fused: one streaming pass over valid rows ----------------
// Per wave: whole rows (online softmax + row argmax, lane-slot parallel, shfl merge).
// Per block: shared LDS colmax (slot-major swizzle -> ~4-way bank aliasing), merged once.
__global__ __launch_bounds__(512, 4) void fused_kernel(const float* __restrict__ wv,
                                                       const float* __restrict__ tgt,
                                                       const int* __restrict__ pm,
                                                       const int* __restrict__ validRows,
                                                       const int* __restrict__ validCnt,
                                                       ull* __restrict__ colPacked,
                                                       float4* __restrict__ points2raw,
                                                       int* __restrict__ ind2to1,
                                                       int N) {
    __shared__ ull colmax[5760];             // N <= 5760, 46 KB -> 3 blocks/CU
    const int b = blockIdx.y;
    const int tid = threadIdx.x;
    const int N4 = N >> 2;

    for (int j = tid; j < N; j += 512) colmax[j] = 0ull;
    __syncthreads();

    const int lane = tid & 63;
    const int wave = tid >> 6;
    const int W = gridDim.x * 8;             // waves per batch
    const int wg = blockIdx.x * 8 + wave;
    const int cnt = validCnt[b];
    const int* vr = validRows + (size_t)b * N;
    const int* m2p = pm + (size_t)(2 * b + 1) * N;
    const float* t0 = tgt + (size_t)b * 3 * N;
    const float* t1 = t0 + N;
    const float* t2 = t1 + N;

    for (int k = wg; k < cnt; k += W) {
        const int i = vr[k];
        const float* row = wv + ((size_t)b * N + i) * N;

        float mA[4], sA[4], p0A[4], p1A[4], p2A[4], bv[4];
        int bi[4];
        #pragma unroll
        for (int q = 0; q < 4; q++) {
            mA[q] = -INFINITY; sA[q] = 0.f; p0A[q] = 0.f; p1A[q] = 0.f; p2A[q] = 0.f;
            bv[q] = -INFINITY; bi[q] = 0;
        }

        for (int j4 = lane; j4 < N4; j4 += 64) {
            float4 r  = ((const float4*)row)[j4];
            int4  mk  = ((const int4*)m2p)[j4];
            float4 a0 = ((const float4*)t0)[j4];
            float4 a1 = ((const float4*)t1)[j4];
            float4 a2 = ((const float4*)t2)[j4];
            const int j = j4 << 2;
            float rr[4] = {r.x, r.y, r.z, r.w};
            int   mm[4] = {mk.x, mk.y, mk.z, mk.w};
            float u0[4] = {a0.x, a0.y, a0.z, a0.w};
            float u1[4] = {a1.x, a1.y, a1.z, a1.w};
            float u2[4] = {a2.x, a2.y, a2.z, a2.w};
            #pragma unroll
            for (int q = 0; q < 4; q++) {
                float rv = rr[q];
                // column argmax candidate (row-mask only; raw value per reference)
                atomicMax(&colmax[q * N4 + j4], packvi(rv, i));
                // row side: m2-masked, scaled
                float x = mm[q] ? (TEMP_F * rv) : XNEG_F;
                if (x > bv[q]) { bv[q] = x; bi[q] = j + q; }
                float mn = fmaxf(mA[q], x);
                float sc = __expf(mA[q] - mn);
                float w  = __expf(x - mn);
                sA[q]  = fmaf(sA[q],  sc, w);
                p0A[q] = fmaf(p0A[q], sc, w * u0[q]);
                p1A[q] = fmaf(p1A[q], sc, w * u1[q]);
                p2A[q] = fmaf(p2A[q], sc, w * u2[q]);
                mA[q] = mn;
            }
        }

        // merge 4 slots
        float M = mA[0], S = sA[0], P0 = p0A[0], P1 = p1A[0], P2 = p2A[0];
        float BV = bv[0]; int BI = bi[0];
        #pragma unroll
        for (int q = 1; q < 4; q++) {
            float mn = fmaxf(M, mA[q]);
            float e1 = __expf(M - mn), e2 = __expf(mA[q] - mn);
            S  = S  * e1 + sA[q]  * e2;
            P0 = P0 * e1 + p0A[q] * e2;
            P1 = P1 * e1 + p1A[q] * e2;
            P2 = P2 * e1 + p2A[q] * e2;
            M = mn;
            if (bv[q] > BV || (bv[q] == BV && bi[q] < BI)) { BV = bv[q]; BI = bi[q]; }
        }
        // butterfly merge across 64 lanes
        for (int off = 32; off > 0; off >>= 1) {
            float Mo  = __shfl_xor(M,  off);
            float So  = __shfl_xor(S,  off);
            float P0o = __shfl_xor(P0, off);
            float P1o = __shfl_xor(P1, off);
            float P2o = __shfl_xor(P2, off);
            float BVo = __shfl_xor(BV, off);
            int   BIo = __shfl_xor(BI, off);
            float mn = fmaxf(M, Mo);
            float e1 = __expf(M - mn), e2 = __expf(Mo - mn);
            S  = S  * e1 + So  * e2;
            P0 = P0 * e1 + P0o * e2;
            P1 = P1 * e1 + P1o * e2;
            P2 = P2 * e1 + P2o * e2;
            M = mn;
            if (BVo > BV || (BVo == BV && BIo < BI)) { BV = BVo; BI = BIo; }
        }
        if (lane == 0) {
            points2raw[(size_t)b * N + i] = make_float4(P0, P1, P2, S);
            ind2to1[(size_t)b * N + i] = BI;
        }
    }

    __syncthreads();
    // merge LDS colmax -> global (unswizzle: stored idx t = q*N4 + j4 represents column 4*j4+q)
    for (int t = tid; t < N; t += 512) {
        ull v = colmax[t];
        if (v) {
            int j = ((t % N4) << 2) | (t / N4);
            atomicMax(&colPacked[(size_t)b * N + j], v);
        }
    }
}

// ---------------- epilogue: mahalanobis + inlier mask + per-pair partial sums ----------------
__global__ __launch_bounds__(256) void loss_kernel(const float* __restrict__ src,
                                                   const float* __restrict__ wts,
                                                   const int* __restrict__ pm,
                                                   const float4* __restrict__ points2raw,
                                                   const int* __restrict__ ind2to1,
                                                   const ull* __restrict__ colPacked,
                                                   const float* __restrict__ T21,
                                                   float* __restrict__ acc, int N) {
    const int b = blockIdx.y;
    const int i = blockIdx.x * 256 + threadIdx.x;
    float lm = 0.f, ld = 0.f, lc = 0.f;
    if (i < N) {
        const int* m1 = pm + (size_t)(2 * b) * N;
        bool msk = (m1[i] != 0);
        int j = msk ? ind2to1[(size_t)b * N + i] : 0;   // guard: poison for invalid rows
        unsigned i2 = 0xFFFFFFFFu - (unsigned)(colPacked[(size_t)b * N + j] & 0xFFFFFFFFull);
        bool consist = ((int)i2 == i);
        const float* T = T21 + b * 12;
        const float* s0 = src + (size_t)b * 3 * N;
        float x = s0[i], y = s0[N + i], z = s0[2 * (size_t)N + i];
        float4 pr = points2raw[(size_t)b * N + i];
        float inv = 1.0f / pr.w;
        float e0 = T[0] * x + T[1] * y + T[2]  * z + T[3]  - pr.x * inv;
        float e1 = T[4] * x + T[5] * y + T[6]  * z + T[7]  - pr.y * inv;
        float e2 = T[8] * x + T[9] * y + T[10] * z + T[11] - pr.z * inv;
        const float* w = wts + (size_t)b * 6 * N;
        float a  = w[i];
        float bb = w[N + i];
        float c  = w[2 * (size_t)N + i];
        float d0 = w[3 * (size_t)N + i];
        float d1 = w[4 * (size_t)N + i];
        float d2 = w[5 * (size_t)N + i];
        float v0 = e0 + a * e1 + bb * e2;
        float v1 = e1 + c * e2;
        float v2 = e2;
        float mah = expf(d0) * v0 * v0 + expf(d1) * v1 * v1 + expf(d2) * v2 * v2;
        if (msk && consist && (mah < THRESH2_F)) {
            lm = mah; ld = d0 + d1 + d2; lc = 1.0f;
        }
    }
    __shared__ float r0[256], r1[256], r2[256];
    const int t = threadIdx.x;
    r0[t] = lm; r1[t] = ld; r2[t] = lc;
    __syncthreads();
    for (int off = 128; off > 0; off >>= 1) {
        if (t < off) { r0[t] += r0[t + off]; r1[t] += r1[t + off]; r2[t] += r2[t + off]; }
        __syncthreads();
    }
    if (t == 0) {
        atomicAdd(&acc[b * 3 + 0], r0[0]);
        atomicAdd(&acc[b * 3 + 1], r1[0]);
        atomicAdd(&acc[b * 3 + 2], r2[0]);
    }
}

__global__ void finish_kernel(const float* __restrict__ acc, float* __restrict__ out, int B) {
    if (threadIdx.x == 0 && blockIdx.x == 0) {
        float total = 0.f;
        for (int b = 0; b < B; b++) {
            float cnt = fmaxf(acc[b * 3 + 2], 1.0f);
            total += (acc[b * 3 + 0] - acc[b * 3 + 1]) / cnt;
        }
        out[0] = total;
    }
}

extern "C" void kernel_launch(void* const* d_in, const int* in_sizes, int n_in,
                              void* d_out, int out_size, void* d_ws, size_t ws_size,
                              hipStream_t stream) {
    const float* src = (const float*)d_in[0];   // (B,3,N)
    const float* tgt = (const float*)d_in[1];   // (B,3,N)
    const float* wts = (const float*)d_in[2];   // (B,6,N)
    const float* wv  = (const float*)d_in[3];   // (B,N,N)
    const float* Tiv = (const float*)d_in[4];   // (2B,4,4)
    const int*   pm  = (const int*)d_in[5];     // (2B,N)
    float* out = (float*)d_out;

    long long s0 = in_sizes[0], s3 = in_sizes[3];
    int N = (int)(3LL * s3 / s0);
    int B = (int)(s0 / (3LL * (long long)N));

    // workspace layout (u64/float4 first for alignment)
    char* w = (char*)d_ws;
    ull* colPacked = (ull*)w;         w += sizeof(ull) * (size_t)B * N;
    float4* points2raw = (float4*)w;  w += sizeof(float4) * (size_t)B * N;
    int* ind2to1 = (int*)w;           w += sizeof(int) * (size_t)B * N;
    int* validRows = (int*)w;         w += sizeof(int) * (size_t)B * N;
    int* validCnt = (int*)w;          w += sizeof(int) * (size_t)B;
    float* T21 = (float*)w;           w += sizeof(float) * (size_t)B * 12;
    float* acc = (float*)w;           w += sizeof(float) * (size_t)B * 3;

    int nb = (N + 255) / 256;
    init_kernel<<<(B * N + 255) / 256, 256, 0, stream>>>(Tiv, colPacked, acc, T21, validCnt, B, N);
    compact_kernel<<<dim3(nb, B), 256, 0, stream>>>(pm, validRows, validCnt, N);

    // fused: 128 blocks/batch x 512 threads = 1024 waves/batch
    dim3 gF(128, B);
    fused_kernel<<<gF, 512, 0, stream>>>(wv, tgt, pm, validRows, validCnt,
                                         colPacked, points2raw, ind2to1, N);

    dim3 gLoss(nb, B);
    loss_kernel<<<gLoss, 256, 0, stream>>>(src, wts, pm, points2raw, ind2to1, colPacked, T21, acc, N);

    finish_kernel<<<1, 64, 0, stream>>>(acc, out, B);
}